// Round 11
// baseline (673.261 us; speedup 1.0000x reference)
//
#include <hip/hip_runtime.h>
#include <hip/hip_bf16.h>

#define BATCH 512
#define TIN   256
#define TOUT  128
#define VOC   256
#define NZ    1024
#define EHID  64
#define DHID  128
#define SDIM  32

typedef __attribute__((ext_vector_type(8))) short bf16x8;
typedef __attribute__((ext_vector_type(4))) float f32x4;

__device__ __forceinline__ float bf2f(unsigned short u) {
  return __uint_as_float(((unsigned)u) << 16);
}
__device__ __forceinline__ unsigned short f2bf(float f) {
  unsigned u = __float_as_uint(f);
  u = u + 0x7FFFu + ((u >> 16) & 1u);
  return (unsigned short)(u >> 16);
}
__device__ __forceinline__ float sigf(float x) { return 1.0f / (1.0f + __expf(-x)); }
__device__ __forceinline__ float tanh_(float x) { return 1.0f - 2.0f / (1.0f + __expf(2.0f * x)); }

// lgkm-only block barrier (no vmcnt drain).
__device__ __forceinline__ void sync_lds() {
  asm volatile("s_waitcnt lgkmcnt(0)\n\ts_barrier" ::: "memory");
}

__device__ __forceinline__ bf16x8 pack8(float4 a, float4 b) {
  bf16x8 r;
  r[0] = (short)f2bf(a.x); r[1] = (short)f2bf(a.y);
  r[2] = (short)f2bf(a.z); r[3] = (short)f2bf(a.w);
  r[4] = (short)f2bf(b.x); r[5] = (short)f2bf(b.y);
  r[6] = (short)f2bf(b.z); r[7] = (short)f2bf(b.w);
  return r;
}

// one-hot row -> index; result broadcast to all lanes of the wave.
__device__ __forceinline__ int dev_findidx(const float* __restrict__ src,
                                           size_t row, int lane) {
  float4 v = ((const float4*)src)[row * 64 + lane];
  int comp = v.x > 0.5f ? 0 : (v.y > 0.5f ? 1 : (v.z > 0.5f ? 2 : 3));
  bool hit = (v.x > 0.5f) || (v.y > 0.5f) || (v.z > 0.5f) || (v.w > 0.5f);
  int cand = hit ? lane * 4 + comp : (1 << 30);
#pragma unroll
  for (int off = 32; off > 0; off >>= 1) {
    int o = __shfl_xor(cand, off);
    cand = cand < o ? cand : o;
  }
  return cand < VOC ? cand : VOC - 1;
}

// ---------------------------------------------------------------------------
// Launch 1: shared tables.
//  blk 0..63   WxT   | 64..191 WdecT | 192..223 WdT | 224..351 gxc GEMM
// ---------------------------------------------------------------------------
__global__ __launch_bounds__(256) void k_tables(
    const float* __restrict__ enc_Wih, const float* __restrict__ enc_b,
    const float* __restrict__ dec_Wih, const float* __restrict__ dec_b,
    const float* __restrict__ out_W, const float* __restrict__ zia,
    float* __restrict__ WxT, float* __restrict__ WdecT, float* __restrict__ WdT,
    float* __restrict__ gxc) {
  int blk = blockIdx.x, tid = threadIdx.x;
  if (blk < 64) {
    __shared__ float T[32][36];
    int r = tid >> 3, c = (tid & 7) * 4;
    int g0 = (blk >> 3) * 32, v0 = (blk & 7) * 32;
    float4 v = *(const float4*)(enc_Wih + (size_t)(g0 + r) * (VOC + NZ) + v0 + c);
    float bias = enc_b[g0 + r];
    T[c + 0][r] = v.x + bias; T[c + 1][r] = v.y + bias;
    T[c + 2][r] = v.z + bias; T[c + 3][r] = v.w + bias;
    __syncthreads();
    *(float4*)(WxT + (size_t)(v0 + r) * 256 + g0 + c) = *(const float4*)&T[r][c];
  } else if (blk < 192) {
    __shared__ float T[32][36];
    int q = blk - 64;
    int r = tid >> 3, c = (tid & 7) * 4;
    int g0 = (q >> 3) * 32, v0 = (q & 7) * 32;
    float4 v = *(const float4*)(dec_Wih + (size_t)(g0 + r) * VOC + v0 + c);
    float bias = dec_b[g0 + r];
    T[c + 0][r] = v.x + bias; T[c + 1][r] = v.y + bias;
    T[c + 2][r] = v.z + bias; T[c + 3][r] = v.w + bias;
    __syncthreads();
    *(float4*)(WdecT + (size_t)(v0 + r) * 512 + g0 + c) = *(const float4*)&T[r][c];
  } else if (blk < 224) {
    __shared__ float T[32][36];
    int q = blk - 192;
    int r = tid >> 3, c = (tid & 7) * 4;
    int v0 = (q >> 2) * 32, k0 = (q & 3) * 32;
    float4 v = *(const float4*)(out_W + (size_t)(v0 + r) * (DHID + SDIM) + k0 + c);
    T[c + 0][r] = v.x; T[c + 1][r] = v.y; T[c + 2][r] = v.z; T[c + 3][r] = v.w;
    __syncthreads();
    *(float4*)(WdT + (size_t)(k0 + r) * 256 + v0 + c) = *(const float4*)&T[r][c];
  } else {
    __shared__ float As[32][36], Bs[32][36];
    int q = blk - 224;
    int b0 = (q & 15) * 32, g0 = (q >> 4) * 32;
    int ldr = tid >> 3, ldc = (tid & 7) * 4;
    int tx = tid & 15, ty = tid >> 4;
    float a00 = 0.f, a01 = 0.f, a10 = 0.f, a11 = 0.f;
    for (int kc = 0; kc < NZ; kc += 32) {
      float4 av = *(const float4*)(zia + (size_t)(b0 + ldr) * NZ + kc + ldc);
      float4 bv = *(const float4*)(enc_Wih + (size_t)(g0 + ldr) * (VOC + NZ) + VOC + kc + ldc);
      __syncthreads();
      As[ldc + 0][ldr] = av.x; As[ldc + 1][ldr] = av.y;
      As[ldc + 2][ldr] = av.z; As[ldc + 3][ldr] = av.w;
      Bs[ldc + 0][ldr] = bv.x; Bs[ldc + 1][ldr] = bv.y;
      Bs[ldc + 2][ldr] = bv.z; Bs[ldc + 3][ldr] = bv.w;
      __syncthreads();
#pragma unroll
      for (int k = 0; k < 32; ++k) {
        float x0 = As[k][tx * 2], x1 = As[k][tx * 2 + 1];
        float y0 = Bs[k][ty * 2], y1 = Bs[k][ty * 2 + 1];
        a00 += x0 * y0; a01 += x0 * y1; a10 += x1 * y0; a11 += x1 * y1;
      }
    }
    float* o = gxc + (size_t)(b0 + tx * 2) * 256 + g0 + ty * 2;
    o[0] = a00; o[1] = a01; o[256] = a10; o[257] = a11;
  }
}

// ---------------------------------------------------------------------------
// Launch 2: MEGA kernel — per block, 4 batches end-to-end.
// Phase 0: findidx (both seqs) -> LDS. Phase 1: enc scan (waves 0-3; waves
// 4-7 barrier-spin). Phase 2: sg/fortza/fout/dh0 block-local. Phase 3:
// dec scan + fused logits (8 waves).
// ---------------------------------------------------------------------------
#define ESTR 72
#define DSTR 136
__global__ __launch_bounds__(512) void k_mega(
    const float* __restrict__ inp_onehot, const float* __restrict__ tgt,
    const float* __restrict__ zia, const float* __restrict__ fortza,
    const float* __restrict__ enc_Whh, const float* __restrict__ WxT,
    const float* __restrict__ gxc,
    const float* __restrict__ sg_W, const float* __restrict__ sg_b,
    const float* __restrict__ out_W, const float* __restrict__ out_b,
    const float* __restrict__ Wc_W, const float* __restrict__ Wc_b,
    const float* __restrict__ dec_Whh, const float* __restrict__ WdecT,
    const float* __restrict__ WdT,
    float* __restrict__ out, float* __restrict__ out_fortza) {
  __shared__ unsigned short hAe[2][16 * ESTR];  //  4.6 KB
  __shared__ unsigned short hAd[2][16 * DSTR];  //  8.7 KB
  __shared__ int   idx_e[4][TIN];               //  4 KB
  __shared__ int   idx_d[4][TOUT];              //  2 KB
  __shared__ float xs[4][EHID + NZ];            // 17.4 KB
  __shared__ float fouts[4][VOC];               //  4 KB
  __shared__ float dh0s[4][DHID];               //  2 KB
  __shared__ float fzs[4][SDIM], fns[4][SDIM];  //  1 KB
  __shared__ float sgs[4][2 * SDIM];            //  1 KB

  int b0 = blockIdx.x * 4;
  int tid = threadIdx.x;
  int w = tid >> 6, lane = tid & 63, n = lane & 15, quad = lane >> 4;

  // ---- Phase 0: findidx into LDS + hAe zero-init ----
  for (int i = tid; i < 2 * 16 * ESTR; i += 512) ((unsigned short*)hAe)[i] = 0;
#pragma unroll 2
  for (int it = 0; it < 128; ++it) {  // 1024 enc positions, 128/wave
    int p = w * 128 + it;
    int b = p >> 8, t = p & 255;
    int idx = dev_findidx(inp_onehot, (size_t)(b0 + b) * TIN + t, lane);
    if (lane == 0) idx_e[b][t] = idx;
  }
#pragma unroll 2
  for (int it = 0; it < 64; ++it) {   // 512 dec positions, 64/wave
    int p = w * 64 + it;
    int b = p >> 7, t = p & 127;
    int idx = dev_findidx(tgt, (size_t)(b0 + b) * TOUT + t, lane);
    if (lane == 0) idx_d[b][t] = idx;
  }
  __syncthreads();

  // ---- Phase 1: encoder scan ----
  if (w < 4) {
    int j = w * 16 + n;
    int arow = n & 12;  // broadcast row (rows !=0 mod 4 never read from D)
    bf16x8 Bf[4][2];
#pragma unroll
    for (int ty = 0; ty < 4; ++ty)
#pragma unroll
      for (int kb = 0; kb < 2; ++kb) {
        const float* s = enc_Whh + (size_t)(ty * 64 + j) * EHID + kb * 32 + quad * 8;
        Bf[ty][kb] = pack8(*(const float4*)s, *(const float4*)(s + 4));
      }
    float gc[4];
#pragma unroll
    for (int ty = 0; ty < 4; ++ty) gc[ty] = gxc[(size_t)(b0 + quad) * 256 + ty * 64 + j];
    float gx[4];
    {
      int id0 = idx_e[quad][0];
#pragma unroll
      for (int ty = 0; ty < 4; ++ty) gx[ty] = WxT[(size_t)id0 * 256 + ty * 64 + j];
    }
    float c0 = 0.0f, h = 0.0f;
    for (int t = 0; t < TIN; ++t) {
      const unsigned short* cur = hAe[t & 1];
      bf16x8 a[2];
#pragma unroll
      for (int kb = 0; kb < 2; ++kb)
        a[kb] = *(const bf16x8*)(cur + arow * ESTR + kb * 32 + quad * 8);
      float gxn[4];
      int tn = (t + 1 < TIN) ? t + 1 : t;
      int idn = idx_e[quad][tn];
#pragma unroll
      for (int ty = 0; ty < 4; ++ty) gxn[ty] = WxT[(size_t)idn * 256 + ty * 64 + j];
      f32x4 acc[4];
#pragma unroll
      for (int ty = 0; ty < 4; ++ty) {
        f32x4 z; z[0] = gx[ty] + gc[ty]; z[1] = 0.f; z[2] = 0.f; z[3] = 0.f;
        z = __builtin_amdgcn_mfma_f32_16x16x32_bf16(a[0], Bf[ty][0], z, 0, 0, 0);
        z = __builtin_amdgcn_mfma_f32_16x16x32_bf16(a[1], Bf[ty][1], z, 0, 0, 0);
        acc[ty] = z;
      }
      float gi = acc[0][0], gf = acc[1][0], gg = acc[2][0], go = acc[3][0];
      c0 = sigf(gf) * c0 + sigf(gi) * tanh_(gg);
      h = sigf(go) * tanh_(c0);
      hAe[(t + 1) & 1][(quad * 4) * ESTR + j] = f2bf(h);
      gx[0] = gxn[0]; gx[1] = gxn[1]; gx[2] = gxn[2]; gx[3] = gxn[3];
      sync_lds();
    }
    xs[quad][j] = h;  // h_enc -> xs[:, 0..63]
  } else {
    for (int t = 0; t < TIN; ++t) sync_lds();  // barrier-matched spin
  }
  __syncthreads();

  // ---- Phase 2: block-local sg / fortza_new / fout / dh0 ----
  // stage zia into xs[:, 64..1087]
  for (int i = tid; i < 1024; i += 512) {  // 4 batches x 256 float4
    int b = i >> 8, q4 = i & 255;
    float4 v = ((const float4*)(zia + (size_t)(b0 + b) * NZ))[q4];
    *(float4*)&xs[b][EHID + q4 * 4] = v;
  }
  if (tid < 128) {
    int b = tid >> 5, s = tid & 31;
    fzs[b][s] = fortza[(size_t)(b0 + b) * SDIM + s];
  }
  __syncthreads();
  // sg: 4 batches x 64 outputs
  if (tid < 256) {
    int b = tid >> 6, o = tid & 63;
    float acc = sg_b[o];
    const float* row = sg_W + (size_t)o * (EHID + SDIM);
#pragma unroll 8
    for (int k = 0; k < EHID; ++k) acc += xs[b][k] * row[k];
#pragma unroll
    for (int k = 0; k < SDIM; ++k) acc += fzs[b][k] * row[EHID + k];
    sgs[b][o] = acc;
  }
  // dh0: 4 batches x 128 outputs (all 512 threads), K=1088
  {
    int b = tid >> 7, v = tid & 127;
    float acc = Wc_b[v];
    const float4* wr = (const float4*)(Wc_W + (size_t)v * (EHID + NZ));
    const float4* x4 = (const float4*)xs[b];
#pragma unroll 8
    for (int k4 = 0; k4 < (EHID + NZ) / 4; ++k4) {
      float4 wv = wr[k4], xv = x4[k4];
      acc += wv.x * xv.x + wv.y * xv.y + wv.z * xv.z + wv.w * xv.w;
    }
    dh0s[b][v] = tanh_(acc);
  }
  __syncthreads();
  if (tid < 128) {
    int b = tid >> 5, s = tid & 31;
    float gate = sigf(sgs[b][s]);
    float upd = tanh_(sgs[b][SDIM + s]);
    float v = gate * fzs[b][s] + (1.0f - gate) * upd;
    fns[b][s] = v;
    out_fortza[(size_t)(b0 + b) * SDIM + s] = v;
  }
  __syncthreads();
  for (int i = tid; i < 4 * VOC; i += 512) {
    int b = i >> 8, v = i & 255;
    float acc = out_b[v];
    const float* row = out_W + (size_t)v * (DHID + SDIM) + DHID;
#pragma unroll
    for (int k = 0; k < SDIM; ++k) acc += fns[b][k] * row[k];
    fouts[b][v] = acc;
  }
  // init dec hA from dh0s
  for (int i = tid; i < 16 * DSTR; i += 512) {
    int m = i / DSTR, k = i - m * DSTR;
    float v = (k < DHID && (m & 3) == 0) ? dh0s[m >> 2][k] : 0.0f;
    hAd[0][i] = f2bf(v);
    hAd[1][i] = 0;
  }
  __syncthreads();

  // ---- Phase 3: decoder scan + fused logits (8 waves) ----
  {
    int j0 = w * 16, j = j0 + n;
    int arow = n & 12;
    bf16x8 Bf[4][4];
#pragma unroll
    for (int ty = 0; ty < 4; ++ty)
#pragma unroll
      for (int kb = 0; kb < 4; ++kb) {
        const float* src = dec_Whh + (size_t)(ty * 128 + j) * DHID + kb * 32 + quad * 8;
        Bf[ty][kb] = pack8(*(const float4*)src, *(const float4*)(src + 4));
      }
    bf16x8 BfL[2][4];
    float fo[2];
    float* op[2];
#pragma unroll
    for (int p = 0; p < 2; ++p) {
      int v = (w * 2 + p) * 16 + n;
#pragma unroll
      for (int kb = 0; kb < 4; ++kb) {
        const float* src = WdT + (size_t)(kb * 32 + quad * 8) * 256 + v;
        bf16x8 r;
#pragma unroll
        for (int i = 0; i < 8; ++i) r[i] = (short)f2bf(src[i * 256]);
        BfL[p][kb] = r;
      }
      fo[p] = fouts[quad][v];
      op[p] = out + (size_t)(b0 + quad) * TOUT * VOC + v;
    }
    float gx[4];
    {
      int id0 = idx_d[quad][0];
#pragma unroll
      for (int ty = 0; ty < 4; ++ty) gx[ty] = WdecT[(size_t)id0 * 512 + ty * 128 + j];
    }
    float c0 = 0.0f;
    for (int t = 0; t < TOUT; ++t) {
      const unsigned short* cur = hAd[t & 1];
      bf16x8 a[4];
#pragma unroll
      for (int kb = 0; kb < 4; ++kb)
        a[kb] = *(const bf16x8*)(cur + arow * DSTR + kb * 32 + quad * 8);
      float gxn[4];
      int tn = (t + 1 < TOUT) ? t + 1 : t;
      int idn = idx_d[quad][tn];
#pragma unroll
      for (int ty = 0; ty < 4; ++ty) gxn[ty] = WdecT[(size_t)idn * 512 + ty * 128 + j];
      f32x4 acc[4];
#pragma unroll
      for (int ty = 0; ty < 4; ++ty) {
        f32x4 z; z[0] = gx[ty]; z[1] = 0.f; z[2] = 0.f; z[3] = 0.f;
#pragma unroll
        for (int kb = 0; kb < 4; ++kb)
          z = __builtin_amdgcn_mfma_f32_16x16x32_bf16(a[kb], Bf[ty][kb], z, 0, 0, 0);
        acc[ty] = z;
      }
      float gi = acc[0][0], gf = acc[1][0], gg = acc[2][0], go = acc[3][0];
      c0 = sigf(gf) * c0 + sigf(gi) * tanh_(gg);
      float h = sigf(go) * tanh_(c0);
      hAd[(t + 1) & 1][(quad * 4) * DSTR + j] = f2bf(h);
      if (t > 0) {
#pragma unroll
        for (int p = 0; p < 2; ++p) {
          f32x4 z; z[0] = fo[p]; z[1] = 0.f; z[2] = 0.f; z[3] = 0.f;
#pragma unroll
          for (int kb = 0; kb < 4; ++kb)
            z = __builtin_amdgcn_mfma_f32_16x16x32_bf16(a[kb], BfL[p][kb], z, 0, 0, 0);
          *op[p] = z[0];
          op[p] += VOC;
        }
      }
      gx[0] = gxn[0]; gx[1] = gxn[1]; gx[2] = gxn[2]; gx[3] = gxn[3];
      sync_lds();
    }
    // epilogue: logits for t = TOUT-1 from h_TOUT (hAd[0], TOUT even)
    const unsigned short* cur = hAd[0];
    bf16x8 a[4];
#pragma unroll
    for (int kb = 0; kb < 4; ++kb)
      a[kb] = *(const bf16x8*)(cur + arow * DSTR + kb * 32 + quad * 8);
#pragma unroll
    for (int p = 0; p < 2; ++p) {
      f32x4 z; z[0] = fo[p]; z[1] = 0.f; z[2] = 0.f; z[3] = 0.f;
#pragma unroll
      for (int kb = 0; kb < 4; ++kb)
        z = __builtin_amdgcn_mfma_f32_16x16x32_bf16(a[kb], BfL[p][kb], z, 0, 0, 0);
      *op[p] = z[0];
    }
  }
}

// ---------------------------------------------------------------------------
extern "C" void kernel_launch(void* const* d_in, const int* in_sizes, int n_in,
                              void* d_out, int out_size, void* d_ws, size_t ws_size,
                              hipStream_t stream) {
  const float* inp_onehot = (const float*)d_in[0];
  const float* zia     = (const float*)d_in[1];
  const float* tgt     = (const float*)d_in[2];
  const float* fortza  = (const float*)d_in[3];
  const float* enc_Wih = (const float*)d_in[4];
  const float* enc_b   = (const float*)d_in[6];
  const float* enc_Whh = (const float*)d_in[5];
  const float* sg_W    = (const float*)d_in[7];
  const float* sg_b    = (const float*)d_in[8];
  const float* Wc_W    = (const float*)d_in[9];
  const float* Wc_b    = (const float*)d_in[10];
  const float* dec_Wih = (const float*)d_in[11];
  const float* dec_Whh = (const float*)d_in[12];
  const float* dec_b   = (const float*)d_in[13];
  const float* out_W   = (const float*)d_in[14];
  const float* out_b   = (const float*)d_in[15];
  float* out = (float*)d_out;

  float* ws = (float*)d_ws;
  float* WxT    = ws;             //  65536 f
  float* WdecT  = ws + 65536;     // 131072 f
  float* WdT    = ws + 196608;    //  32768 f
  float* gxc    = ws + 229376;    // 131072 f  (total ~1.4 MB)

  k_tables<<<352, 256, 0, stream>>>(enc_Wih, enc_b, dec_Wih, dec_b, out_W, zia,
                                    WxT, WdecT, WdT, gxc);
  k_mega<<<BATCH / 4, 512, 0, stream>>>(
      inp_onehot, tgt, zia, fortza, enc_Whh, WxT, gxc,
      sg_W, sg_b, out_W, out_b, Wc_W, Wc_b, dec_Whh, WdecT, WdT,
      out, out + (size_t)BATCH * TOUT * VOC);
}